// Round 17
// baseline (2590.694 us; speedup 1.0000x reference)
//
#include <hip/hip_runtime.h>
#include <stdint.h>

#define L 18
#define DIM (1 << L)
#define MKRY 64
#define NBLK 256
#define TPB 1024

// ---------------- threefry2x32 (JAX) ----------------
__device__ __forceinline__ uint32_t rotl32(uint32_t v, int r){ return (v<<r)|(v>>(32-r)); }

__device__ __forceinline__ void threefry2x32(uint32_t k0, uint32_t k1, uint32_t x0, uint32_t x1,
                                             uint32_t& o0, uint32_t& o1) {
  uint32_t k2 = k0 ^ k1 ^ 0x1BD11BDAu;
  x0 += k0; x1 += k1;
  x0+=x1; x1=rotl32(x1,13); x1^=x0;
  x0+=x1; x1=rotl32(x1,15); x1^=x0;
  x0+=x1; x1=rotl32(x1,26); x1^=x0;
  x0+=x1; x1=rotl32(x1,6);  x1^=x0;
  x0+=k1; x1+=k2+1u;
  x0+=x1; x1=rotl32(x1,17); x1^=x0;
  x0+=x1; x1=rotl32(x1,29); x1^=x0;
  x0+=x1; x1=rotl32(x1,16); x1^=x0;
  x0+=x1; x1=rotl32(x1,24); x1^=x0;
  x0+=k2; x1+=k0+2u;
  x0+=x1; x1=rotl32(x1,13); x1^=x0;
  x0+=x1; x1=rotl32(x1,15); x1^=x0;
  x0+=x1; x1=rotl32(x1,26); x1^=x0;
  x0+=x1; x1=rotl32(x1,6);  x1^=x0;
  x0+=k0; x1+=k1+3u;
  x0+=x1; x1=rotl32(x1,17); x1^=x0;
  x0+=x1; x1=rotl32(x1,29); x1^=x0;
  x0+=x1; x1=rotl32(x1,16); x1^=x0;
  x0+=x1; x1=rotl32(x1,24); x1^=x0;
  x0+=k1; x1+=k2+4u;
  x0+=x1; x1=rotl32(x1,13); x1^=x0;
  x0+=x1; x1=rotl32(x1,15); x1^=x0;
  x0+=x1; x1=rotl32(x1,26); x1^=x0;
  x0+=x1; x1=rotl32(x1,6);  x1^=x0;
  x0+=k2; x1+=k0+5u;
  o0=x0; o1=x1;
}

__device__ float jax_erfinv(float x){
  #pragma clang fp contract(off)
  float w = -log1pf(-x*x);
  float p;
  if (w < 5.0f) {
    w = w - 2.5f;
    p = 2.81022636e-08f;
    p = 3.43273939e-07f + p*w;
    p = -3.5233877e-06f + p*w;
    p = -4.39150654e-06f + p*w;
    p = 0.00021858087f + p*w;
    p = -0.00125372503f + p*w;
    p = -0.00417768164f + p*w;
    p = 0.246640727f + p*w;
    p = 1.50140941f + p*w;
  } else {
    w = sqrtf(w) - 3.0f;
    p = -0.000200214257f;
    p = 0.000100950558f + p*w;
    p = 0.00134934322f + p*w;
    p = -0.00367342844f + p*w;
    p = 0.00573950773f + p*w;
    p = -0.0076224613f + p*w;
    p = 0.00943887047f + p*w;
    p = 1.00167406f + p*w;
    p = 2.83297682f + p*w;
  }
  return p*x;
}

__device__ __forceinline__ float rng_val(unsigned i){
  #pragma clang fp contract(off)
  uint32_t o0,o1; threefry2x32(0u,42u,0u,i,o0,o1);
  uint32_t bits = o0 ^ o1;
  float f = __uint_as_float((bits >> 9) | 0x3f800000u) - 1.0f;
  const float lo = -0.99999994f;
  float u = f*2.0f;
  u = u + lo;
  u = fmaxf(lo, u);
  return 1.41421354f * jax_erfinv(u);
}

// Deterministic block reduce of two doubles; result broadcast to all threads.
__device__ __forceinline__ double2 blockReduce2(double a, double b){
  __shared__ double sa[16], sb[16], res[2];
  int lane = threadIdx.x & 63, wid = threadIdx.x >> 6;
  #pragma unroll
  for (int off=32; off; off>>=1){ a += __shfl_down(a,off,64); b += __shfl_down(b,off,64); }
  if (lane==0){ sa[wid]=a; sb[wid]=b; }
  __syncthreads();
  if (wid==0){
    double xa = (lane<16)? sa[lane] : 0.0;
    double xb = (lane<16)? sb[lane] : 0.0;
    #pragma unroll
    for (int off=8; off; off>>=1){ xa += __shfl_down(xa,off,64); xb += __shfl_down(xb,off,64); }
    if (lane==0){ res[0]=xa; res[1]=xb; }
  }
  __syncthreads();
  double2 r; r.x=res[0]; r.y=res[1];
  return r;
}

// ---------------- barrier primitives ----------------
// pass1 region layout (uints, 128B-line granularity):
//   bar[g*32]           g=0..7 : arrival stripes (monotonic)
//   bar[256 + g*32]     g=0..7 : flag lines   (epoch: all w visible)
//   bar[512 + g*32 +0]  g=0..7 : release epoch | +1 = alpha bits | +2 = beta bits
// pass2c uses its own region at bar+1024 (stripes + [256] release).
__device__ __forceinline__ void p1_arrive(unsigned* bar){
  __hip_atomic_fetch_add(&bar[(blockIdx.x & 7)*32], 1u, __ATOMIC_ACQ_REL, __HIP_MEMORY_SCOPE_AGENT);
}
__device__ __forceinline__ void p1_wait_arrivals(unsigned* bar, unsigned target){
  unsigned guard=0;
  for (;;){
    unsigned sum=0;
    #pragma unroll
    for (int k=0;k<8;++k)
      sum += __hip_atomic_load(&bar[k*32], __ATOMIC_RELAXED, __HIP_MEMORY_SCOPE_AGENT);
    if (sum >= target) break;
    if (++guard > (1u<<24)) break;
  }
  (void)__hip_atomic_load(&bar[0], __ATOMIC_ACQUIRE, __HIP_MEMORY_SCOPE_AGENT);
}
__device__ __forceinline__ void p1_spin(unsigned* ctr, unsigned target){
  unsigned guard=0;
  while (__hip_atomic_load(ctr, __ATOMIC_RELAXED, __HIP_MEMORY_SCOPE_AGENT) < target){
    if (++guard > (1u<<24)) break;
  }
  (void)__hip_atomic_load(ctr, __ATOMIC_ACQUIRE, __HIP_MEMORY_SCOPE_AGENT);
}

// classic two-sided barrier for pass2c (own region barc: stripes + barc[256])
__device__ __forceinline__ void gbar2(unsigned* bar, unsigned epoch){
  __syncthreads();
  if (threadIdx.x==0){
    const int st = (blockIdx.x & 7)*32;
    __hip_atomic_fetch_add(&bar[st], 1u, __ATOMIC_ACQ_REL, __HIP_MEMORY_SCOPE_AGENT);
    if (blockIdx.x==0){
      unsigned guard=0;
      for (;;){
        unsigned sum=0;
        #pragma unroll
        for (int k=0;k<8;++k)
          sum += __hip_atomic_load(&bar[k*32], __ATOMIC_ACQUIRE, __HIP_MEMORY_SCOPE_AGENT);
        if (sum >= (unsigned)NBLK) break;
        __builtin_amdgcn_s_sleep(1);
        if (++guard > (1u<<22)) break;
      }
      #pragma unroll
      for (int k=0;k<8;++k)
        __hip_atomic_store(&bar[k*32], 0u, __ATOMIC_RELAXED, __HIP_MEMORY_SCOPE_AGENT);
      __hip_atomic_fetch_add(&bar[256], 1u, __ATOMIC_RELEASE, __HIP_MEMORY_SCOPE_AGENT);
    } else {
      unsigned guard=0;
      while (__hip_atomic_load(&bar[256], __ATOMIC_RELAXED, __HIP_MEMORY_SCOPE_AGENT) < epoch){
        __builtin_amdgcn_s_sleep(1);
        if (++guard > (1u<<22)) break;
      }
      (void)__hip_atomic_load(&bar[256], __ATOMIC_ACQUIRE, __HIP_MEMORY_SCOPE_AGENT);
    }
  }
  __syncthreads();
}

// cross-block masks for span 1024: bonds 3<<(16-i) i=0..7, fields 1<<(17-i) i=0..7
#define CM_INIT {3u<<16,3u<<15,3u<<14,3u<<13,3u<<12,3u<<11,3u<<10,3u<<9, \
                 1u<<17,1u<<16,1u<<15,1u<<14,1u<<13,1u<<12,1u<<11,1u<<10}

// Matrix-free H row; per-element FP order identical to all passed rounds.
__device__ __forceinline__ float matvec1(int s, int tid, float vs,
                                         const float* __restrict__ lds_v,
                                         const float (*__restrict__ lds_hv)[TPB],
                                         const float* __restrict__ hxz){
  #pragma clang fp contract(off)
  float acc = 0.0f;
  #pragma unroll
  for (int i=0;i<L-1;++i){
    const int q = L-2-i;
    const unsigned msk = 3u<<q;
    const unsigned b2 = ((unsigned)s >> q) & 3u;
    float nbv;
    if (i<=7) nbv = lds_hv[i][tid];
    else      nbv = lds_v[((unsigned)s ^ msk) & (TPB-1u)];
    if (b2==0u || b2==3u){ acc = acc + 0.25f*vs; }
    else if (b2==1u){ float t = -0.25f*vs; t = t + 0.5f*nbv; acc = acc + t; }
    else            { float t = 0.5f*nbv; t = t + (-0.25f)*vs; acc = acc + t; }
  }
  #pragma unroll
  for (int i=0;i<L;++i){
    const int p = L-1-i;
    const unsigned msk = 1u<<p;
    const float hx = hxz[i], hz = hxz[18+i];
    float nbv;
    if (i<=7) nbv = lds_hv[8+i][tid];
    else      nbv = lds_v[((unsigned)s ^ msk) & (TPB-1u)];
    float t;
    if ((unsigned)s & msk){ t = hx*nbv; t = t + (-hz)*vs; }
    else                  { t = hz*vs;  t = t + hx*nbv; }
    acc = acc + t;
  }
  return acc;
}

// scal layout (floats): [0..63] alphas | [64..127] betas | [129] nrm |
// [130..147] hx | [148..165] hz | [192..447] U (64x4)

__global__ void k_init(unsigned* bar){
  int t = threadIdx.x;
  bar[t] = 0u;
  bar[t+1024] = 0u;
}

// part (doubles): [0..511] parity0 | [512..1023] parity1 / rng
__global__ void __launch_bounds__(TPB) k_pass1(const float* __restrict__ B0,
        const float* __restrict__ Bext, const float* __restrict__ phi,
        float* __restrict__ vbase, int vmod, float* __restrict__ wring,
        double* __restrict__ part, float* scal, unsigned* bar){
  __shared__ float lds_v[TPB];
  __shared__ float lds_hv[16][TPB];    // current halo value
  __shared__ float lds_hvp[16][TPB];   // previous halo value
  __shared__ float lds_hxz[36];
  __shared__ float lds_ab2[2];
  const unsigned CM[16] = CM_INIT;
  const int tid = threadIdx.x, bid = blockIdx.x;
  const int s = bid*TPB + tid;
  const int grp = (bid & 7)*32;

  if (bid==0 && tid < L){
    #pragma clang fp contract(off)
    float b0 = B0[0], be = Bext[0];
    double ph = (double)phi[tid];
    float Bx = b0*(float)sin(ph);
    float Bz = b0*(float)cos(ph);
    Bz = Bz + be;
    scal[130+tid] = 0.5f*Bx;
    scal[148+tid] = 0.5f*Bz;
  }

  float n = rng_val((unsigned)s);
  {
    double2 pr = blockReduce2((double)n*(double)n, 0.0);
    if (tid==0){ part[512+2*bid]=pr.x; part[512+2*bid+1]=pr.y; }
  }
  // ---- epoch 1 (RNG): single-sided, block0 reduces -> nrm (packed release) ----
  float nrm;
  if (bid==0){
    if (tid==0){
      p1_arrive(bar);
      p1_wait_arrivals(bar, (unsigned)NBLK*1u);
      #pragma unroll
      for (int g=0; g<8; ++g)
        __hip_atomic_store(&bar[256+g*32], 1u, __ATOMIC_RELEASE, __HIP_MEMORY_SCOPE_AGENT);
    }
    __syncthreads();
    double xa = (tid<NBLK)? part[512+2*tid] : 0.0;
    double xb = (tid<NBLK)? part[512+2*tid+1] : 0.0;
    double2 t2 = blockReduce2(xa, xb);
    nrm = (float)sqrt(t2.x);
    if (tid==0){
      scal[129] = nrm;
      unsigned nb = __float_as_uint(nrm);
      #pragma unroll
      for (int g=0; g<8; ++g){
        __hip_atomic_store(&bar[512+g*32+1], nb, __ATOMIC_RELAXED, __HIP_MEMORY_SCOPE_AGENT);
        __hip_atomic_store(&bar[512+g*32],   1u, __ATOMIC_RELEASE, __HIP_MEMORY_SCOPE_AGENT);
      }
    }
  } else {
    if (tid==0){
      p1_arrive(bar);
      p1_spin(&bar[512+grp], 1u);
      lds_ab2[0] = __uint_as_float(
        __hip_atomic_load(&bar[512+grp+1], __ATOMIC_RELAXED, __HIP_MEMORY_SCOPE_AGENT));
    }
    __syncthreads();
    nrm = lds_ab2[0];
  }

  if (tid < 36) lds_hxz[tid] = scal[130+tid];

  float v = __fdiv_rn(n, nrm), vp = 0.0f, b_p = 0.0f;
  vbase[s] = v;                  // slot 0 = v_0

  #pragma unroll
  for (int ci=0; ci<16; ++ci){
    lds_hv[ci][tid]  = __fdiv_rn(rng_val((unsigned)s ^ CM[ci]), nrm);
    lds_hvp[ci][tid] = 0.0f;
  }
  lds_v[tid] = v;
  __syncthreads();

  for (int m=0; m<MKRY; ++m){
    float w = matvec1(s, tid, v, lds_v, lds_hv, lds_hxz);
    wring[(size_t)(m&1)*DIM + s] = w;

    double2 p2 = blockReduce2((double)v*(double)w, (double)w*(double)w);
    double* pb = part + (size_t)(m&1)*512;
    if (tid==0){ pb[2*bid]=p2.x; pb[2*bid+1]=p2.y; }

    const unsigned e = 2u + (unsigned)m;
    const float* wr = wring + (size_t)(m&1)*DIM;
    float wn[16];
    float alpha, beta;

    if (bid==0){
      if (tid==0){
        p1_arrive(bar);
        p1_wait_arrivals(bar, (unsigned)NBLK*e);
        #pragma unroll
        for (int g=0; g<8; ++g)
          __hip_atomic_store(&bar[256+g*32], e, __ATOMIC_RELEASE, __HIP_MEMORY_SCOPE_AGENT);
      }
      __syncthreads();
      double xa = (tid<NBLK)? pb[2*tid] : 0.0;
      double xb = (tid<NBLK)? pb[2*tid+1] : 0.0;
      double2 tt = blockReduce2(xa, xb);
      alpha = (float)tt.x;
      double b2d = tt.y - tt.x*tt.x - (double)b_p*(double)b_p;
      beta = (float)sqrt(fmax(b2d, 0.0));
      if (tid==0){
        scal[m] = alpha; scal[64+m] = beta;
        unsigned ab = __float_as_uint(alpha), bb = __float_as_uint(beta);
        #pragma unroll
        for (int g=0; g<8; ++g){
          __hip_atomic_store(&bar[512+g*32+1], ab, __ATOMIC_RELAXED, __HIP_MEMORY_SCOPE_AGENT);
          __hip_atomic_store(&bar[512+g*32+2], bb, __ATOMIC_RELAXED, __HIP_MEMORY_SCOPE_AGENT);
          __hip_atomic_store(&bar[512+g*32],   e,  __ATOMIC_RELEASE, __HIP_MEMORY_SCOPE_AGENT);
        }
      }
      #pragma unroll
      for (int ci=0; ci<16; ++ci) wn[ci] = wr[(unsigned)s ^ CM[ci]];
    } else {
      if (tid==0){
        p1_arrive(bar);
        p1_spin(&bar[256+grp], e);     // flag: all w visible
      }
      __syncthreads();
      #pragma unroll
      for (int ci=0; ci<16; ++ci) wn[ci] = wr[(unsigned)s ^ CM[ci]];   // overlap block0's reduce
      if (tid==0){
        p1_spin(&bar[512+grp], e);     // release: alpha/beta in same line
        lds_ab2[0] = __uint_as_float(
          __hip_atomic_load(&bar[512+grp+1], __ATOMIC_RELAXED, __HIP_MEMORY_SCOPE_AGENT));
        lds_ab2[1] = __uint_as_float(
          __hip_atomic_load(&bar[512+grp+2], __ATOMIC_RELAXED, __HIP_MEMORY_SCOPE_AGENT));
      }
      __syncthreads();
      alpha = lds_ab2[0]; beta = lds_ab2[1];
    }
    float bden = fmaxf(beta, 1e-12f);

    float vn;
    {
      #pragma clang fp contract(off)
      float x = w - alpha*v;
      x = x - b_p*vp;
      vn = __fdiv_rn(x, bden);
    }
    vbase[(size_t)((m+1)%vmod)*DIM + s] = vn;

    // halo advance: same formula as owner -> bit-identical v_{m+1}[nb]
    #pragma unroll
    for (int ci=0; ci<16; ++ci){
      #pragma clang fp contract(off)
      float hv = lds_hv[ci][tid];
      float x = wn[ci] - alpha*hv;
      x = x - b_p*lds_hvp[ci][tid];
      float hn = __fdiv_rn(x, bden);
      lds_hvp[ci][tid] = hv;
      lds_hv[ci][tid] = hn;
    }

    vp=v; v=vn; b_p=beta;
    lds_v[tid]=vn;
    __syncthreads();
  }
}

// big-ws: V fully stored, pass2 is a trivial accumulate
__global__ void __launch_bounds__(256) k_pass2s(const float* __restrict__ vbase,
        const float* __restrict__ scal, float* __restrict__ out){
  __shared__ float U[256];
  int tid = threadIdx.x;
  int s = blockIdx.x*256 + tid;
  U[tid] = scal[192+tid];
  __syncthreads();
  {
    #pragma clang fp contract(off)
    float o0=0.0f,o1=0.0f,o2=0.0f,o3=0.0f;
    for (int m=0;m<MKRY;++m){
      float vm = vbase[(size_t)m*DIM + s];
      o0 = o0 + vm*U[4*m+0];
      o1 = o1 + vm*U[4*m+1];
      o2 = o2 + vm*U[4*m+2];
      o3 = o3 + vm*U[4*m+3];
    }
    *(float4*)(out + 4 + 4*(size_t)s) = make_float4(o0,o1,o2,o3);
  }
}

// small-ws fallback: same LDS-halo scheme, alphas/betas known, 1 barrier/iter.
__global__ void __launch_bounds__(TPB) k_pass2c(float* __restrict__ wring,
        const float* __restrict__ scal, float* __restrict__ out, unsigned* barc){
  __shared__ float lds_v[TPB];
  __shared__ float lds_hv[16][TPB];
  __shared__ float lds_hvp[16][TPB];
  __shared__ float lds_hxz[36];
  __shared__ float lds_ab[384];
  const unsigned CM[16] = CM_INIT;
  const int tid = threadIdx.x, bid = blockIdx.x;
  const int s = bid*TPB + tid;
  if (tid < 36) lds_hxz[tid] = scal[130+tid];
  if (tid < 128) lds_ab[tid] = scal[tid];
  if (tid >= 128 && tid < 384) lds_ab[tid] = scal[192 + (tid-128)];
  const float nrm = scal[129];
  float v = __fdiv_rn(rng_val((unsigned)s), nrm), vp = 0.0f;
  #pragma unroll
  for (int ci=0; ci<16; ++ci){
    lds_hv[ci][tid]  = __fdiv_rn(rng_val((unsigned)s ^ CM[ci]), nrm);
    lds_hvp[ci][tid] = 0.0f;
  }
  lds_v[tid] = v;
  __syncthreads();
  float o0=0.0f,o1=0.0f,o2=0.0f,o3=0.0f;
  for (int m=0;m<MKRY;++m){
    float w = matvec1(s, tid, v, lds_v, lds_hv, lds_hxz);
    wring[(size_t)(m&1)*DIM + s] = w;
    {
      #pragma clang fp contract(off)
      o0 = o0 + v*lds_ab[128+4*m+0];
      o1 = o1 + v*lds_ab[128+4*m+1];
      o2 = o2 + v*lds_ab[128+4*m+2];
      o3 = o3 + v*lds_ab[128+4*m+3];
    }
    gbar2(barc, 1+(unsigned)m);
    float wn[16];
    const float* wr = wring + (size_t)(m&1)*DIM;
    #pragma unroll
    for (int ci=0; ci<16; ++ci) wn[ci] = wr[(unsigned)s ^ CM[ci]];
    float alpha = lds_ab[m];
    float bp = (m==0)? 0.0f : lds_ab[64+m-1];
    float bden = fmaxf(lds_ab[64+m], 1e-12f);
    float vn;
    {
      #pragma clang fp contract(off)
      float x = w - alpha*v;
      x = x - bp*vp;
      vn = __fdiv_rn(x, bden);
    }
    #pragma unroll
    for (int ci=0; ci<16; ++ci){
      #pragma clang fp contract(off)
      float hv = lds_hv[ci][tid];
      float x = wn[ci] - alpha*hv;
      x = x - bp*lds_hvp[ci][tid];
      float hn = __fdiv_rn(x, bden);
      lds_hvp[ci][tid] = hv;
      lds_hv[ci][tid] = hn;
    }
    vp=v; v=vn;
    lds_v[tid]=vn;
    __syncthreads();
  }
  *(float4*)(out + 4 + 4*(size_t)s) = make_float4(o0,o1,o2,o3);
}

// tql2 (EISPACK) f64 — R14/R16-proven fused register variant (absmax 4.88e-4):
// dd/ee register-resident with shfl prefetch, lane-predicated updates, Z rotation
// fused in-loop via zhi carry. rsqrt = f32 seed + ONE f64 NR. Z stored f32.
// Tail: 4 smallest eigenpairs via masked wave-argmin (first-min-index).
__global__ void k_eigh(float* __restrict__ scal, float* __restrict__ out){
  __shared__ float Zf[64][65];
  int t = threadIdx.x;
  double ddv = (double)scal[t];
  double eev = (t<63)? (double)scal[64+t] : 0.0;
  for (int j=0;j<64;++j) Zf[t][j] = (t==j)?1.0f:0.0f;
  __syncthreads();

  for (int l=0;l<64;++l){
    for (int iter=0; iter<80; ++iter){
      double dt1 = __shfl_down(ddv, 1, 64);
      bool cond = (t>=l) && (t<63) &&
                  (fabs(eev) <= 2.220446049250313e-16 * (fabs(ddv)+fabs(dt1)));
      unsigned long long bm = __ballot(cond) | (1ull<<63);
      int m = (int)__builtin_ctzll(bm);
      if (m==l) break;
      double dd_l  = __shfl(ddv, l, 64);
      double dd_l1 = __shfl(ddv, l+1, 64);
      double dd_m  = __shfl(ddv, m, 64);
      double ee_l  = __shfl(eev, l, 64);
      double g = (dd_l1-dd_l)/(2.0*ee_l);
      double r = sqrt(fma(g,g,1.0));
      g = dd_m-dd_l + ee_l/(g + copysign(r,g));
      double s=1.0, c=1.0, p=0.0;
      int stop = l;
      double ee_i  = __shfl(eev, m-1, 64);
      double dd_i  = __shfl(ddv, m-1, 64);
      double dd_i1 = dd_m;
      double zhi = (double)Zf[t][m];
      for (int i=m-1; i>=l; --i){
        double ee_n=0.0, dd_n=0.0;
        if (i>l){ ee_n = __shfl(eev, i-1, 64); dd_n = __shfl(ddv, i-1, 64); }
        double f = s*ee_i, b = c*ee_i;
        double h = fma(f,f,g*g);
        if (h==0.0){
          if (t==i+1) ddv = dd_i1 - p;
          if (t==m) eev = 0.0;
          stop = i+1;
          break;
        }
        double inv;
        if (h < 1e-35){
          inv = 1.0/sqrt(h);
        } else {
          double x0 = (double)__frsqrt_rn((float)h);
          inv = x0*(1.5 - (0.5*h)*(x0*x0));   // one f64 NR: ~5e-15 rel
        }
        s = f*inv; c = g*inv;
        double rr = h*inv;            // = sqrt(h)
        g = dd_i1 - p;
        double r2 = (dd_i - g)*s + 2.0*c*b;
        p = s*r2;
        double ddw = g + p;
        g = c*r2 - b;
        if (t==i+1){ ddv = ddw; eev = rr; }
        // Z rotation i on own row (carry); f64 math, f32 storage
        double zlo = (double)Zf[t][i];
        Zf[t][i+1] = (float)(s*zlo + c*zhi);
        zhi = c*zlo - s*zhi;
        dd_i1 = dd_i; ee_i = ee_n; dd_i = dd_n;
        if (i==l){
          if (t==l){ ddv = ddv - p; eev = g; }
          if (t==m){ eev = 0.0; }
        }
      }
      Zf[t][stop] = (float)zhi;
      __syncthreads();
    }
  }
  // extract 4 smallest eigenpairs (ascending, first-min-index tie-break)
  double dvm = ddv;
  #pragma unroll
  for (int k=0;k<4;++k){
    double mv = dvm; int mi = t;
    #pragma unroll
    for (int off=32; off; off>>=1){
      double ov = __shfl_down(mv, off, 64);
      int    oi = __shfl_down(mi, off, 64);
      if (ov < mv || (ov==mv && oi<mi)){ mv=ov; mi=oi; }
    }
    int jm = __shfl(mi, 0, 64);
    double lv = __shfl(mv, 0, 64);
    if (t==jm) dvm = 1.0e300;
    scal[192 + t*4 + k] = Zf[t][jm];
    if (t==k) out[k] = (float)lv;
  }
}

extern "C" void kernel_launch(void* const* d_in, const int* in_sizes, int n_in,
                              void* d_out, int out_size, void* d_ws, size_t ws_size,
                              hipStream_t stream){
  (void)in_sizes; (void)n_in; (void)out_size;
  const float* B0   = (const float*)d_in[0];
  const float* Bext = (const float*)d_in[1];
  const float* phi  = (const float*)d_in[2];
  float* out = (float*)d_out;

  size_t need_big = ((size_t)(MKRY+3)*DIM)*4 + 32768;
  int vmod; bool big;
  if (ws_size >= need_big) { vmod = MKRY+1; big = true; }
  else                     { vmod = 3;      big = false; }

  float* vbase = (float*)d_ws;
  float* wring = vbase + (size_t)vmod*DIM;
  double* part = (double*)(wring + 2*(size_t)DIM);
  float* scal  = (float*)(part + 1024);
  unsigned* bar = (unsigned*)(scal + 512);

  hipLaunchKernelGGL(k_init, dim3(1), dim3(1024), 0, stream, bar);
  {
    void* args[] = { (void*)&B0, (void*)&Bext, (void*)&phi,
                     (void*)&vbase, (void*)&vmod, (void*)&wring,
                     (void*)&part, (void*)&scal, (void*)&bar };
    (void)hipLaunchCooperativeKernel((const void*)k_pass1, dim3(NBLK), dim3(TPB), args, 0, stream);
  }
  hipLaunchKernelGGL(k_eigh, dim3(1), dim3(64), 0, stream, scal, out);
  if (big){
    hipLaunchKernelGGL(k_pass2s, dim3(DIM/256), dim3(256), 0, stream, vbase, scal, out);
  } else {
    unsigned* barc = bar + 1024;
    void* args[] = { (void*)&wring, (void*)&scal, (void*)&out, (void*)&barc };
    (void)hipLaunchCooperativeKernel((const void*)k_pass2c, dim3(NBLK), dim3(TPB), args, 0, stream);
  }
}

// Round 18
// 2256.114 us; speedup vs baseline: 1.1483x; 1.1483x over previous
//
#include <hip/hip_runtime.h>
#include <stdint.h>

#define L 18
#define DIM (1 << L)
#define MKRY 64
#define NBLK 256
#define TPB 1024

// ---------------- threefry2x32 (JAX) ----------------
__device__ __forceinline__ uint32_t rotl32(uint32_t v, int r){ return (v<<r)|(v>>(32-r)); }

__device__ __forceinline__ void threefry2x32(uint32_t k0, uint32_t k1, uint32_t x0, uint32_t x1,
                                             uint32_t& o0, uint32_t& o1) {
  uint32_t k2 = k0 ^ k1 ^ 0x1BD11BDAu;
  x0 += k0; x1 += k1;
  x0+=x1; x1=rotl32(x1,13); x1^=x0;
  x0+=x1; x1=rotl32(x1,15); x1^=x0;
  x0+=x1; x1=rotl32(x1,26); x1^=x0;
  x0+=x1; x1=rotl32(x1,6);  x1^=x0;
  x0+=k1; x1+=k2+1u;
  x0+=x1; x1=rotl32(x1,17); x1^=x0;
  x0+=x1; x1=rotl32(x1,29); x1^=x0;
  x0+=x1; x1=rotl32(x1,16); x1^=x0;
  x0+=x1; x1=rotl32(x1,24); x1^=x0;
  x0+=k2; x1+=k0+2u;
  x0+=x1; x1=rotl32(x1,13); x1^=x0;
  x0+=x1; x1=rotl32(x1,15); x1^=x0;
  x0+=x1; x1=rotl32(x1,26); x1^=x0;
  x0+=x1; x1=rotl32(x1,6);  x1^=x0;
  x0+=k0; x1+=k1+3u;
  x0+=x1; x1=rotl32(x1,17); x1^=x0;
  x0+=x1; x1=rotl32(x1,29); x1^=x0;
  x0+=x1; x1=rotl32(x1,16); x1^=x0;
  x0+=x1; x1=rotl32(x1,24); x1^=x0;
  x0+=k1; x1+=k2+4u;
  x0+=x1; x1=rotl32(x1,13); x1^=x0;
  x0+=x1; x1=rotl32(x1,15); x1^=x0;
  x0+=x1; x1=rotl32(x1,26); x1^=x0;
  x0+=x1; x1=rotl32(x1,6);  x1^=x0;
  x0+=k2; x1+=k0+5u;
  o0=x0; o1=x1;
}

__device__ float jax_erfinv(float x){
  #pragma clang fp contract(off)
  float w = -log1pf(-x*x);
  float p;
  if (w < 5.0f) {
    w = w - 2.5f;
    p = 2.81022636e-08f;
    p = 3.43273939e-07f + p*w;
    p = -3.5233877e-06f + p*w;
    p = -4.39150654e-06f + p*w;
    p = 0.00021858087f + p*w;
    p = -0.00125372503f + p*w;
    p = -0.00417768164f + p*w;
    p = 0.246640727f + p*w;
    p = 1.50140941f + p*w;
  } else {
    w = sqrtf(w) - 3.0f;
    p = -0.000200214257f;
    p = 0.000100950558f + p*w;
    p = 0.00134934322f + p*w;
    p = -0.00367342844f + p*w;
    p = 0.00573950773f + p*w;
    p = -0.0076224613f + p*w;
    p = 0.00943887047f + p*w;
    p = 1.00167406f + p*w;
    p = 2.83297682f + p*w;
  }
  return p*x;
}

__device__ __forceinline__ float rng_val(unsigned i){
  #pragma clang fp contract(off)
  uint32_t o0,o1; threefry2x32(0u,42u,0u,i,o0,o1);
  uint32_t bits = o0 ^ o1;
  float f = __uint_as_float((bits >> 9) | 0x3f800000u) - 1.0f;
  const float lo = -0.99999994f;
  float u = f*2.0f;
  u = u + lo;
  u = fmaxf(lo, u);
  return 1.41421354f * jax_erfinv(u);
}

// Deterministic block reduce of two doubles; result broadcast to all threads.
__device__ __forceinline__ double2 blockReduce2(double a, double b){
  __shared__ double sa[16], sb[16], res[2];
  int lane = threadIdx.x & 63, wid = threadIdx.x >> 6;
  #pragma unroll
  for (int off=32; off; off>>=1){ a += __shfl_down(a,off,64); b += __shfl_down(b,off,64); }
  if (lane==0){ sa[wid]=a; sb[wid]=b; }
  __syncthreads();
  if (wid==0){
    double xa = (lane<16)? sa[lane] : 0.0;
    double xb = (lane<16)? sb[lane] : 0.0;
    #pragma unroll
    for (int off=8; off; off>>=1){ xa += __shfl_down(xa,off,64); xb += __shfl_down(xb,off,64); }
    if (lane==0){ res[0]=xa; res[1]=xb; }
  }
  __syncthreads();
  double2 r; r.x=res[0]; r.y=res[1];
  return r;
}

// ---------------- barrier primitives (R16 protocol) ----------------
// pass1 region: stripes bar[0,32,..,224] (monotonic), release bar[256], flag bar[288]
__device__ __forceinline__ void p1_arrive(unsigned* bar){
  __hip_atomic_fetch_add(&bar[(blockIdx.x & 7)*32], 1u, __ATOMIC_ACQ_REL, __HIP_MEMORY_SCOPE_AGENT);
}
__device__ __forceinline__ void p1_wait_arrivals(unsigned* bar, unsigned target){
  unsigned guard=0;
  for (;;){
    unsigned sum=0;
    #pragma unroll
    for (int k=0;k<8;++k)
      sum += __hip_atomic_load(&bar[k*32], __ATOMIC_RELAXED, __HIP_MEMORY_SCOPE_AGENT);
    if (sum >= target) break;
    if (++guard > (1u<<24)) break;
  }
  (void)__hip_atomic_load(&bar[0], __ATOMIC_ACQUIRE, __HIP_MEMORY_SCOPE_AGENT);
}
__device__ __forceinline__ void p1_spin(unsigned* ctr, unsigned target){
  unsigned guard=0;
  while (__hip_atomic_load(ctr, __ATOMIC_RELAXED, __HIP_MEMORY_SCOPE_AGENT) < target){
    if (++guard > (1u<<24)) break;
  }
  (void)__hip_atomic_load(ctr, __ATOMIC_ACQUIRE, __HIP_MEMORY_SCOPE_AGENT);
}

// classic two-sided barrier for pass2c (own region barc: stripes + barc[256])
__device__ __forceinline__ void gbar2(unsigned* bar, unsigned epoch){
  __syncthreads();
  if (threadIdx.x==0){
    const int st = (blockIdx.x & 7)*32;
    __hip_atomic_fetch_add(&bar[st], 1u, __ATOMIC_ACQ_REL, __HIP_MEMORY_SCOPE_AGENT);
    if (blockIdx.x==0){
      unsigned guard=0;
      for (;;){
        unsigned sum=0;
        #pragma unroll
        for (int k=0;k<8;++k)
          sum += __hip_atomic_load(&bar[k*32], __ATOMIC_ACQUIRE, __HIP_MEMORY_SCOPE_AGENT);
        if (sum >= (unsigned)NBLK) break;
        __builtin_amdgcn_s_sleep(1);
        if (++guard > (1u<<22)) break;
      }
      #pragma unroll
      for (int k=0;k<8;++k)
        __hip_atomic_store(&bar[k*32], 0u, __ATOMIC_RELAXED, __HIP_MEMORY_SCOPE_AGENT);
      __hip_atomic_fetch_add(&bar[256], 1u, __ATOMIC_RELEASE, __HIP_MEMORY_SCOPE_AGENT);
    } else {
      unsigned guard=0;
      while (__hip_atomic_load(&bar[256], __ATOMIC_RELAXED, __HIP_MEMORY_SCOPE_AGENT) < epoch){
        __builtin_amdgcn_s_sleep(1);
        if (++guard > (1u<<22)) break;
      }
      (void)__hip_atomic_load(&bar[256], __ATOMIC_ACQUIRE, __HIP_MEMORY_SCOPE_AGENT);
    }
  }
  __syncthreads();
}

// cross-block masks for span 1024: bonds 3<<(16-i) i=0..7, fields 1<<(17-i) i=0..7
#define CM_INIT {3u<<16,3u<<15,3u<<14,3u<<13,3u<<12,3u<<11,3u<<10,3u<<9, \
                 1u<<17,1u<<16,1u<<15,1u<<14,1u<<13,1u<<12,1u<<11,1u<<10}

// Matrix-free H row; per-element FP order identical to all passed rounds.
__device__ __forceinline__ float matvec1(int s, int tid, float vs,
                                         const float* __restrict__ lds_v,
                                         const float (*__restrict__ lds_hv)[TPB],
                                         const float* __restrict__ hxz){
  #pragma clang fp contract(off)
  float acc = 0.0f;
  #pragma unroll
  for (int i=0;i<L-1;++i){
    const int q = L-2-i;
    const unsigned msk = 3u<<q;
    const unsigned b2 = ((unsigned)s >> q) & 3u;
    float nbv;
    if (i<=7) nbv = lds_hv[i][tid];
    else      nbv = lds_v[((unsigned)s ^ msk) & (TPB-1u)];
    if (b2==0u || b2==3u){ acc = acc + 0.25f*vs; }
    else if (b2==1u){ float t = -0.25f*vs; t = t + 0.5f*nbv; acc = acc + t; }
    else            { float t = 0.5f*nbv; t = t + (-0.25f)*vs; acc = acc + t; }
  }
  #pragma unroll
  for (int i=0;i<L;++i){
    const int p = L-1-i;
    const unsigned msk = 1u<<p;
    const float hx = hxz[i], hz = hxz[18+i];
    float nbv;
    if (i<=7) nbv = lds_hv[8+i][tid];
    else      nbv = lds_v[((unsigned)s ^ msk) & (TPB-1u)];
    float t;
    if ((unsigned)s & msk){ t = hx*nbv; t = t + (-hz)*vs; }
    else                  { t = hz*vs;  t = t + hx*nbv; }
    acc = acc + t;
  }
  return acc;
}

// scal layout (floats): [0..63] alphas | [64..127] betas | [129] nrm |
// [130..147] hx | [148..165] hz | [192..447] U (64x4)

__global__ void k_init(unsigned* bar){
  int t = threadIdx.x;
  bar[t] = 0u;
  bar[t+1024] = 0u;
}

// part (doubles): [0..511] parity0 | [512..1023] parity1 / rng
__global__ void __launch_bounds__(TPB) k_pass1(const float* __restrict__ B0,
        const float* __restrict__ Bext, const float* __restrict__ phi,
        float* __restrict__ vbase, int vmod, float* __restrict__ wring,
        double* __restrict__ part, float* scal, unsigned* bar){
  __shared__ float lds_v[TPB];
  __shared__ float lds_hv[16][TPB];    // current halo value
  __shared__ float lds_hvp[16][TPB];   // previous halo value
  __shared__ float lds_hxz[36];
  const unsigned CM[16] = CM_INIT;
  const int tid = threadIdx.x, bid = blockIdx.x;
  const int s = bid*TPB + tid;

  if (bid==0 && tid < L){
    #pragma clang fp contract(off)
    float b0 = B0[0], be = Bext[0];
    double ph = (double)phi[tid];
    float Bx = b0*(float)sin(ph);
    float Bz = b0*(float)cos(ph);
    Bz = Bz + be;
    scal[130+tid] = 0.5f*Bx;
    scal[148+tid] = 0.5f*Bz;
  }

  float n = rng_val((unsigned)s);
  {
    double2 pr = blockReduce2((double)n*(double)n, 0.0);
    if (tid==0){ part[512+2*bid]=pr.x; part[512+2*bid+1]=pr.y; }
  }
  // ---- epoch 1 (RNG): single-sided, block0 reduces -> nrm ----
  float nrm;
  if (bid==0){
    if (tid==0){
      p1_arrive(bar);
      p1_wait_arrivals(bar, (unsigned)NBLK*1u);
      __hip_atomic_fetch_add(&bar[288], 1u, __ATOMIC_RELEASE, __HIP_MEMORY_SCOPE_AGENT); // flag=1
    }
    __syncthreads();
    double xa = (tid<NBLK)? part[512+2*tid] : 0.0;
    double xb = (tid<NBLK)? part[512+2*tid+1] : 0.0;
    double2 t2 = blockReduce2(xa, xb);
    nrm = (float)sqrt(t2.x);
    if (tid==0){
      scal[129] = nrm;
      __hip_atomic_fetch_add(&bar[256], 1u, __ATOMIC_RELEASE, __HIP_MEMORY_SCOPE_AGENT); // rel=1
    }
  } else {
    if (tid==0){
      p1_arrive(bar);
      p1_spin(&bar[256], 1u);
    }
    __syncthreads();
    nrm = scal[129];
  }

  if (tid < 36) lds_hxz[tid] = scal[130+tid];

  float v = __fdiv_rn(n, nrm), vp = 0.0f, b_p = 0.0f;
  vbase[s] = v;                  // slot 0 = v_0

  #pragma unroll
  for (int ci=0; ci<16; ++ci){
    lds_hv[ci][tid]  = __fdiv_rn(rng_val((unsigned)s ^ CM[ci]), nrm);
    lds_hvp[ci][tid] = 0.0f;
  }
  lds_v[tid] = v;
  __syncthreads();

  for (int m=0; m<MKRY; ++m){
    float w = matvec1(s, tid, v, lds_v, lds_hv, lds_hxz);
    wring[(size_t)(m&1)*DIM + s] = w;

    double2 p2 = blockReduce2((double)v*(double)w, (double)w*(double)w);
    double* pb = part + (size_t)(m&1)*512;
    if (tid==0){ pb[2*bid]=p2.x; pb[2*bid+1]=p2.y; }

    const unsigned e = 2u + (unsigned)m;
    const float* wr = wring + (size_t)(m&1)*DIM;
    float wn[16];
    float alpha, beta;

    if (bid==0){
      if (tid==0){
        p1_arrive(bar);
        p1_wait_arrivals(bar, (unsigned)NBLK*e);
        __hip_atomic_fetch_add(&bar[288], 1u, __ATOMIC_RELEASE, __HIP_MEMORY_SCOPE_AGENT); // flag=e
      }
      __syncthreads();
      double xa = (tid<NBLK)? pb[2*tid] : 0.0;
      double xb = (tid<NBLK)? pb[2*tid+1] : 0.0;
      double2 tt = blockReduce2(xa, xb);
      alpha = (float)tt.x;
      double b2d = tt.y - tt.x*tt.x - (double)b_p*(double)b_p;
      beta = (float)sqrt(fmax(b2d, 0.0));
      if (tid==0){
        scal[m] = alpha; scal[64+m] = beta;
        __hip_atomic_fetch_add(&bar[256], 1u, __ATOMIC_RELEASE, __HIP_MEMORY_SCOPE_AGENT); // rel=e
      }
      #pragma unroll
      for (int ci=0; ci<16; ++ci) wn[ci] = wr[(unsigned)s ^ CM[ci]];
    } else {
      if (tid==0){
        p1_arrive(bar);
        p1_spin(&bar[288], e);     // arrival flag: all w visible
      }
      __syncthreads();
      #pragma unroll
      for (int ci=0; ci<16; ++ci) wn[ci] = wr[(unsigned)s ^ CM[ci]];   // gathers overlap block0's reduce
      if (tid==0){
        p1_spin(&bar[256], e);     // release: alpha/beta ready
      }
      __syncthreads();
      alpha = scal[m]; beta = scal[64+m];
    }
    float bden = fmaxf(beta, 1e-12f);

    float vn;
    {
      #pragma clang fp contract(off)
      float x = w - alpha*v;
      x = x - b_p*vp;
      vn = __fdiv_rn(x, bden);
    }
    vbase[(size_t)((m+1)%vmod)*DIM + s] = vn;

    // halo advance: same formula as owner -> bit-identical v_{m+1}[nb]
    #pragma unroll
    for (int ci=0; ci<16; ++ci){
      #pragma clang fp contract(off)
      float hv = lds_hv[ci][tid];
      float x = wn[ci] - alpha*hv;
      x = x - b_p*lds_hvp[ci][tid];
      float hn = __fdiv_rn(x, bden);
      lds_hvp[ci][tid] = hv;
      lds_hv[ci][tid] = hn;
    }

    vp=v; v=vn; b_p=beta;
    lds_v[tid]=vn;
    __syncthreads();
  }
}

// big-ws: V fully stored, pass2 is a trivial accumulate
__global__ void __launch_bounds__(256) k_pass2s(const float* __restrict__ vbase,
        const float* __restrict__ scal, float* __restrict__ out){
  __shared__ float U[256];
  int tid = threadIdx.x;
  int s = blockIdx.x*256 + tid;
  U[tid] = scal[192+tid];
  __syncthreads();
  {
    #pragma clang fp contract(off)
    float o0=0.0f,o1=0.0f,o2=0.0f,o3=0.0f;
    for (int m=0;m<MKRY;++m){
      float vm = vbase[(size_t)m*DIM + s];
      o0 = o0 + vm*U[4*m+0];
      o1 = o1 + vm*U[4*m+1];
      o2 = o2 + vm*U[4*m+2];
      o3 = o3 + vm*U[4*m+3];
    }
    *(float4*)(out + 4 + 4*(size_t)s) = make_float4(o0,o1,o2,o3);
  }
}

// small-ws fallback: same LDS-halo scheme, alphas/betas known, 1 barrier/iter.
__global__ void __launch_bounds__(TPB) k_pass2c(float* __restrict__ wring,
        const float* __restrict__ scal, float* __restrict__ out, unsigned* barc){
  __shared__ float lds_v[TPB];
  __shared__ float lds_hv[16][TPB];
  __shared__ float lds_hvp[16][TPB];
  __shared__ float lds_hxz[36];
  __shared__ float lds_ab[384];
  const unsigned CM[16] = CM_INIT;
  const int tid = threadIdx.x, bid = blockIdx.x;
  const int s = bid*TPB + tid;
  if (tid < 36) lds_hxz[tid] = scal[130+tid];
  if (tid < 128) lds_ab[tid] = scal[tid];
  if (tid >= 128 && tid < 384) lds_ab[tid] = scal[192 + (tid-128)];
  const float nrm = scal[129];
  float v = __fdiv_rn(rng_val((unsigned)s), nrm), vp = 0.0f;
  #pragma unroll
  for (int ci=0; ci<16; ++ci){
    lds_hv[ci][tid]  = __fdiv_rn(rng_val((unsigned)s ^ CM[ci]), nrm);
    lds_hvp[ci][tid] = 0.0f;
  }
  lds_v[tid] = v;
  __syncthreads();
  float o0=0.0f,o1=0.0f,o2=0.0f,o3=0.0f;
  for (int m=0;m<MKRY;++m){
    float w = matvec1(s, tid, v, lds_v, lds_hv, lds_hxz);
    wring[(size_t)(m&1)*DIM + s] = w;
    {
      #pragma clang fp contract(off)
      o0 = o0 + v*lds_ab[128+4*m+0];
      o1 = o1 + v*lds_ab[128+4*m+1];
      o2 = o2 + v*lds_ab[128+4*m+2];
      o3 = o3 + v*lds_ab[128+4*m+3];
    }
    gbar2(barc, 1+(unsigned)m);
    float wn[16];
    const float* wr = wring + (size_t)(m&1)*DIM;
    #pragma unroll
    for (int ci=0; ci<16; ++ci) wn[ci] = wr[(unsigned)s ^ CM[ci]];
    float alpha = lds_ab[m];
    float bp = (m==0)? 0.0f : lds_ab[64+m-1];
    float bden = fmaxf(lds_ab[64+m], 1e-12f);
    float vn;
    {
      #pragma clang fp contract(off)
      float x = w - alpha*v;
      x = x - bp*vp;
      vn = __fdiv_rn(x, bden);
    }
    #pragma unroll
    for (int ci=0; ci<16; ++ci){
      #pragma clang fp contract(off)
      float hv = lds_hv[ci][tid];
      float x = wn[ci] - alpha*hv;
      x = x - bp*lds_hvp[ci][tid];
      float hn = __fdiv_rn(x, bden);
      lds_hvp[ci][tid] = hv;
      lds_hv[ci][tid] = hn;
    }
    vp=v; v=vn;
    lds_v[tid]=vn;
    __syncthreads();
  }
  *(float4*)(out + 4 + 4*(size_t)s) = make_float4(o0,o1,o2,o3);
}

// tql2 (EISPACK) f64 — fused register variant with LDS SNAPSHOT prefetch.
// All within-sweep dd/ee reads see PRE-SWEEP values (updates only touch i+1 >
// reads at i-1), so dd/ee are snapshotted to LDS once per sweep and the
// per-rotation __shfl prefetches become loop-invariant broadcast ds_reads the
// compiler can hoist/prefetch (the shfls' register inputs changed every
// iteration, blocking hoisting). Rotation FP sequence identical to R16.
// Z stored f32 (f64 math). Tail: 4 smallest via masked wave-argmin.
__global__ void k_eigh(float* __restrict__ scal, float* __restrict__ out){
  __shared__ float Zf[64][65];
  __shared__ double dsnap[64], esnap[64];
  int t = threadIdx.x;
  double ddv = (double)scal[t];
  double eev = (t<63)? (double)scal[64+t] : 0.0;
  for (int j=0;j<64;++j) Zf[t][j] = (t==j)?1.0f:0.0f;
  __syncthreads();

  for (int l=0;l<64;++l){
    for (int iter=0; iter<80; ++iter){
      double dt1 = __shfl_down(ddv, 1, 64);
      bool cond = (t>=l) && (t<63) &&
                  (fabs(eev) <= 2.220446049250313e-16 * (fabs(ddv)+fabs(dt1)));
      unsigned long long bm = __ballot(cond) | (1ull<<63);
      int m = (int)__builtin_ctzll(bm);
      if (m==l) break;
      // snapshot pre-sweep dd/ee (reads below provably see pre-sweep values)
      dsnap[t] = ddv; esnap[t] = eev;
      __syncthreads();
      double dd_l  = dsnap[l];
      double dd_l1 = dsnap[l+1];
      double dd_m  = dsnap[m];
      double ee_l  = esnap[l];
      double g = (dd_l1-dd_l)/(2.0*ee_l);
      double r = sqrt(fma(g,g,1.0));
      g = dd_m-dd_l + ee_l/(g + copysign(r,g));
      double s=1.0, c=1.0, p=0.0;
      int stop = l;
      double ee_i  = esnap[m-1];
      double dd_i  = dsnap[m-1];
      double dd_i1 = dd_m;
      int pf = (m-2 < 0)? 0 : m-2;
      double eeN = esnap[pf];
      double ddN = dsnap[pf];
      double zhi = (double)Zf[t][m];
      for (int i=m-1; i>=l; --i){
        double f = s*ee_i, b = c*ee_i;
        double h = fma(f,f,g*g);
        if (h==0.0){
          if (t==i+1) ddv = dd_i1 - p;
          if (t==m) eev = 0.0;
          stop = i+1;
          break;
        }
        double inv;
        if (h < 1e-35){
          inv = 1.0/sqrt(h);
        } else {
          double x0 = (double)__frsqrt_rn((float)h);
          inv = x0*(1.5 - (0.5*h)*(x0*x0));   // one f64 NR: ~5e-15 rel
        }
        s = f*inv; c = g*inv;
        double rr = h*inv;            // = sqrt(h)
        g = dd_i1 - p;
        double r2 = (dd_i - g)*s + 2.0*c*b;
        p = s*r2;
        double ddw = g + p;
        double gn = c*r2 - b;
        if (t==i+1){ ddv = ddw; eev = rr; }
        // Z rotation i on own row (carry); f64 math, f32 storage
        double zlo = (double)Zf[t][i];
        Zf[t][i+1] = (float)(s*zlo + c*zhi);
        zhi = c*zlo - s*zhi;
        dd_i1 = dd_i; ee_i = eeN; dd_i = ddN;
        int nx = (i-2 < 0)? 0 : i-2;
        eeN = esnap[nx];
        ddN = dsnap[nx];
        g = gn;
        if (i==l){
          if (t==l){ ddv = ddv - p; eev = g; }
          if (t==m){ eev = 0.0; }
        }
      }
      Zf[t][stop] = (float)zhi;
      __syncthreads();
    }
  }
  // extract 4 smallest eigenpairs (ascending, first-min-index tie-break)
  double dvm = ddv;
  #pragma unroll
  for (int k=0;k<4;++k){
    double mv = dvm; int mi = t;
    #pragma unroll
    for (int off=32; off; off>>=1){
      double ov = __shfl_down(mv, off, 64);
      int    oi = __shfl_down(mi, off, 64);
      if (ov < mv || (ov==mv && oi<mi)){ mv=ov; mi=oi; }
    }
    int jm = __shfl(mi, 0, 64);
    double lv = __shfl(mv, 0, 64);
    if (t==jm) dvm = 1.0e300;
    scal[192 + t*4 + k] = Zf[t][jm];
    if (t==k) out[k] = (float)lv;
  }
}

extern "C" void kernel_launch(void* const* d_in, const int* in_sizes, int n_in,
                              void* d_out, int out_size, void* d_ws, size_t ws_size,
                              hipStream_t stream){
  (void)in_sizes; (void)n_in; (void)out_size;
  const float* B0   = (const float*)d_in[0];
  const float* Bext = (const float*)d_in[1];
  const float* phi  = (const float*)d_in[2];
  float* out = (float*)d_out;

  size_t need_big = ((size_t)(MKRY+3)*DIM)*4 + 32768;
  int vmod; bool big;
  if (ws_size >= need_big) { vmod = MKRY+1; big = true; }
  else                     { vmod = 3;      big = false; }

  float* vbase = (float*)d_ws;
  float* wring = vbase + (size_t)vmod*DIM;
  double* part = (double*)(wring + 2*(size_t)DIM);
  float* scal  = (float*)(part + 1024);
  unsigned* bar = (unsigned*)(scal + 512);

  hipLaunchKernelGGL(k_init, dim3(1), dim3(1024), 0, stream, bar);
  {
    void* args[] = { (void*)&B0, (void*)&Bext, (void*)&phi,
                     (void*)&vbase, (void*)&vmod, (void*)&wring,
                     (void*)&part, (void*)&scal, (void*)&bar };
    (void)hipLaunchCooperativeKernel((const void*)k_pass1, dim3(NBLK), dim3(TPB), args, 0, stream);
  }
  hipLaunchKernelGGL(k_eigh, dim3(1), dim3(64), 0, stream, scal, out);
  if (big){
    hipLaunchKernelGGL(k_pass2s, dim3(DIM/256), dim3(256), 0, stream, vbase, scal, out);
  } else {
    unsigned* barc = bar + 1024;
    void* args[] = { (void*)&wring, (void*)&scal, (void*)&out, (void*)&barc };
    (void)hipLaunchCooperativeKernel((const void*)k_pass2c, dim3(NBLK), dim3(TPB), args, 0, stream);
  }
}